// Round 5
// baseline (9842.825 us; speedup 1.0000x reference)
//
#include <hip/hip_runtime.h>

// 2-layer tanh RNN, B=64 T=512 H=512, f32 in/out.
// Weights split hi+lo bf16 (w=hi+lo) -> 2 MFMA passes/operand, f32-grade acc.
// Fused pipeline: 64 WGs x 256 thr; blocks 0..31 layer 0, 32..63 layer 1
// (xw1 fused as concat-K MFMA, one step behind layer 0). h rings bf16.
// R4->R5: h traffic switched from per-fragment device-scope ATOMIC loads
// (not clustered by compiler => 16-32 serialized ~800cy IF$ round-trips/step,
// 10.9us/step) to PLAIN vector loads/stores + agent-scope fence protocol
// (producer: threadfence->syncthreads->release-add; consumer: acquire-spin->
// syncthreads->threadfence->loads). Loads now pipeline into one latency.

#define HD 512
#define BATCH 64
#define SEQ 512
#define NVOCAB 25
#define OUTD 1000
#define NWG 32
#define BH (BATCH * HD)

typedef unsigned short u16;
typedef unsigned int u32;
typedef unsigned long long u64;
typedef __attribute__((ext_vector_type(8))) short short8;  // 8 bf16
typedef __attribute__((ext_vector_type(4))) float f32x4;

union FragU { u16 h[8]; u64 q[2]; short8 v; };

__device__ __forceinline__ float bf2f(u16 v) {
    union { u32 u; float f; } c; c.u = ((u32)v) << 16; return c.f;
}
__device__ __forceinline__ u16 f2bf(float f) {
    union { float f; u32 u; } c; c.f = f;
    return (u16)((c.u + 0x7FFFu + ((c.u >> 16) & 1u)) >> 16);  // RNE
}

// Zero header+rings; global thread 1024 probes x's int width:
// int64 little-endian => odd int32 words of small nonneg values are all 0.
__global__ void init_kernel(u32* p, int n, const int* x32, int* flag) {
    int i = blockIdx.x * 256 + threadIdx.x;
    if (i == 1024) {
        int all0 = 1;
        for (int j = 0; j < 64; ++j) if (x32[2 * j + 1] != 0) all0 = 0;
        *flag = all0;
    } else if (i < n) p[i] = 0u;
}

__global__ __launch_bounds__(256, 1) void rnn_fused(
    const float* __restrict__ Whh0, const float* __restrict__ Wih0,
    const int* __restrict__ x,
    const float* __restrict__ bih0, const float* __restrict__ bhh0,
    const float* __restrict__ Whh1, const float* __restrict__ Wih1,
    const float* __restrict__ bih1, const float* __restrict__ bhh1,
    u16* h1ring, u16* h2ring, float* h2final, int* hdr)
{
    int* c0 = hdr;
    int* c1 = hdr + 512;
    const int tid  = threadIdx.x;
    const int wave = tid >> 6;
    const int lane = tid & 63;
    const int quad = lane >> 4;
    const int l16  = lane & 15;
    const int layer = blockIdx.x >> 5;          // 0 or 1
    const int rowbase = (blockIdx.x & 31) * 16; // 32 WGs x 16 rows = 512
    const int arow = rowbase + l16;             // A row (m = lane&15)
    const int row0 = rowbase + quad * 4;        // C/D rows: quad*4 + reg
    const int col  = wave * 16 + l16;           // C/D col (batch)

    __shared__ u16 ldsW[2][16][4][16][8];       // Wih1 hi/lo frags, 32 KB

    // Whh split hi/lo bf16, register-resident: A[m=lane&15][k=quad*8+j].
    const float* Wself = layer ? Whh1 : Whh0;
    short8 Ah[16], Al[16];
    #pragma unroll
    for (int kc = 0; kc < 16; ++kc) {
        FragU th, tl;
        #pragma unroll
        for (int j = 0; j < 8; ++j) {
            float w = Wself[arow * HD + kc * 32 + quad * 8 + j];
            u16 hi = f2bf(w);
            th.h[j] = hi;
            tl.h[j] = f2bf(w - bf2f(hi));
        }
        Ah[kc] = th.v; Al[kc] = tl.v;
    }
    if (layer && wave == 0) {  // all 4 waves share the same A rows
        #pragma unroll
        for (int kc = 0; kc < 16; ++kc) {
            FragU th, tl;
            #pragma unroll
            for (int j = 0; j < 8; ++j) {
                float w = Wih1[arow * HD + kc * 32 + quad * 8 + j];
                u16 hi = f2bf(w);
                th.h[j] = hi;
                tl.h[j] = f2bf(w - bf2f(hi));
            }
            *(short8*)&ldsW[0][kc][quad][l16][0] = th.v;
            *(short8*)&ldsW[1][kc][quad][l16][0] = tl.v;
        }
    }
    const float* bA = layer ? bih1 : bih0;
    const float* bB = layer ? bhh1 : bhh0;
    float bsum[4];
    #pragma unroll
    for (int i = 0; i < 4; ++i) bsum[i] = bA[row0 + i] + bB[row0 + i];
    const int is64 = hdr[1024];
    __syncthreads();

    for (int t = 0; t < SEQ; ++t) {
        // ---- wait: tid0 acquire-spins on producer flags ----
        if (tid == 0) {
            long g = 0;
            if (layer == 0) {
                if (t > 0)
                    while (__hip_atomic_load(c0 + (t - 1), __ATOMIC_ACQUIRE,
                               __HIP_MEMORY_SCOPE_AGENT) < NWG && ++g < (1L << 24)) {}
                if (t >= 2)  // WAR: layer-1 readers of h1[t-1] retired
                    while (__hip_atomic_load(c1 + (t - 2), __ATOMIC_ACQUIRE,
                               __HIP_MEMORY_SCOPE_AGENT) < NWG && ++g < (1L << 24)) {}
            } else {
                if (t > 0)
                    while (__hip_atomic_load(c1 + (t - 1), __ATOMIC_ACQUIRE,
                               __HIP_MEMORY_SCOPE_AGENT) < NWG && ++g < (1L << 24)) {}
                while (__hip_atomic_load(c0 + t, __ATOMIC_ACQUIRE,
                           __HIP_MEMORY_SCOPE_AGENT) < NWG && ++g < (1L << 24)) {}
            }
        }
        __syncthreads();
        __threadfence();  // agent acquire: invalidate stale cached h lines

        // ---- compute ----
        f32x4 acc = {0.f, 0.f, 0.f, 0.f};
        float pre[4];
        if (layer == 0) {
            const u16* hp = h1ring + (size_t)(t & 1) * BH + col * HD;  // h1[t]
            #pragma unroll
            for (int kc = 0; kc < 16; ++kc) {
                short8 bfrag = *(const short8*)(hp + kc * 32 + quad * 8);
                acc = __builtin_amdgcn_mfma_f32_16x16x32_bf16(Ah[kc], bfrag, acc, 0, 0, 0);
                acc = __builtin_amdgcn_mfma_f32_16x16x32_bf16(Al[kc], bfrag, acc, 0, 0, 0);
            }
            int xi = is64 ? (int)((const long long*)x)[col * SEQ + t]
                          : x[col * SEQ + t];               // x[b][t]
            #pragma unroll
            for (int i = 0; i < 4; ++i)
                pre[i] = acc[i] + bsum[i] + Wih0[(row0 + i) * NVOCAB + xi];
        } else {
            const u16* hp = h2ring + (size_t)(t & 1) * BH + col * HD;        // h2[t]
            const u16* hq = h1ring + (size_t)((t + 1) & 1) * BH + col * HD;  // h1[t+1]
            #pragma unroll
            for (int kc = 0; kc < 16; ++kc) {
                short8 b2 = *(const short8*)(hp + kc * 32 + quad * 8);
                short8 b1 = *(const short8*)(hq + kc * 32 + quad * 8);
                acc = __builtin_amdgcn_mfma_f32_16x16x32_bf16(Ah[kc], b2, acc, 0, 0, 0);
                acc = __builtin_amdgcn_mfma_f32_16x16x32_bf16(Al[kc], b2, acc, 0, 0, 0);
                short8 w1h = *(short8*)&ldsW[0][kc][quad][l16][0];
                short8 w1l = *(short8*)&ldsW[1][kc][quad][l16][0];
                acc = __builtin_amdgcn_mfma_f32_16x16x32_bf16(w1h, b1, acc, 0, 0, 0);
                acc = __builtin_amdgcn_mfma_f32_16x16x32_bf16(w1l, b1, acc, 0, 0, 0);
            }
            #pragma unroll
            for (int i = 0; i < 4; ++i) pre[i] = acc[i] + bsum[i];
        }
        float hf[4]; u16 hv[4];
        #pragma unroll
        for (int i = 0; i < 4; ++i) { hf[i] = tanhf(pre[i]); hv[i] = f2bf(hf[i]); }
        u32 lo = (u32)hv[0] | ((u32)hv[1] << 16);
        u32 hi = (u32)hv[2] | ((u32)hv[3] << 16);
        u16* dst = (layer == 0)
            ? h1ring + (size_t)((t + 1) & 1) * BH + col * HD + row0
            : h2ring + (size_t)((t + 1) & 1) * BH + col * HD + row0;
        *(uint2*)dst = make_uint2(lo, hi);
        if (layer == 1 && t == SEQ - 1)
            *(f32x4*)(h2final + col * HD + row0) = *(f32x4*)hf;  // exact final h2

        // ---- publish: release protocol ----
        __threadfence();   // per-thread agent release: h stores to coherent point
        __syncthreads();   // all 256 threads' fences done
        if (tid == 0) {
            int* ctr = (layer == 0) ? (c0 + t) : (c1 + t);
            __hip_atomic_fetch_add(ctr, 1, __ATOMIC_RELEASE, __HIP_MEMORY_SCOPE_AGENT);
        }
    }
}

__global__ __launch_bounds__(256) void out_kernel(
    const float* __restrict__ h2last, const float* __restrict__ Wout,
    const float* __restrict__ bout, float* __restrict__ out)
{
    int o = blockIdx.x * 256 + threadIdx.x;
    int b = blockIdx.y;
    if (o >= OUTD) return;
    const float* hrow = h2last + b * HD;
    const float* wrow = Wout + o * HD;
    float acc = 0.f;
    for (int k = 0; k < HD; k += 4) {
        float4 hv = *(const float4*)(hrow + k);
        float4 wv = *(const float4*)(wrow + k);
        acc += hv.x * wv.x + hv.y * wv.y + hv.z * wv.z + hv.w * wv.w;
    }
    out[b * OUTD + o] = acc + bout[o];
}

extern "C" void kernel_launch(void* const* d_in, const int* in_sizes, int n_in,
                              void* d_out, int out_size, void* d_ws, size_t ws_size,
                              hipStream_t stream) {
    const int*   x     = (const int*)d_in[0];
    const float* W_ih0 = (const float*)d_in[1];
    const float* W_hh0 = (const float*)d_in[2];
    const float* b_ih0 = (const float*)d_in[3];
    const float* b_hh0 = (const float*)d_in[4];
    const float* W_ih1 = (const float*)d_in[5];
    const float* W_hh1 = (const float*)d_in[6];
    const float* b_ih1 = (const float*)d_in[7];
    const float* b_hh1 = (const float*)d_in[8];
    const float* W_out = (const float*)d_in[9];
    const float* b_out = (const float*)d_in[10];

    // ws: hdr[2048] int (c0[512] c1[512] flag@1024) | h1ring 2xBH bf16 |
    //     h2ring 2xBH bf16 | h2final BH f32
    const size_t needed = 8192 + (size_t)2 * BH * 2 * 2 + (size_t)BH * 4;  // 392 KB
    if (ws_size < needed) return;  // signature: absmax=0.149 non-NaN => ws short

    int* hdr = (int*)d_ws;
    u16* h1ring = (u16*)((char*)d_ws + 8192);
    u16* h2ring = h1ring + (size_t)2 * BH;
    float* h2final = (float*)(h2ring + (size_t)2 * BH);

    const int nzero = (8192 + 4 * BH * 2) / 4;  // hdr + both rings, in words
    init_kernel<<<(nzero + 255) / 256, 256, 0, stream>>>((u32*)d_ws, nzero, x, hdr + 1024);
    rnn_fused<<<2 * NWG, 256, 0, stream>>>(W_hh0, W_ih0, x, b_ih0, b_hh0,
                                           W_hh1, W_ih1, b_ih1, b_hh1,
                                           h1ring, h2ring, h2final, hdr);
    out_kernel<<<dim3(4, BATCH), 256, 0, stream>>>(h2final, W_out, b_out, (float*)d_out);
}

// Round 6
// 5478.768 us; speedup vs baseline: 1.7965x; 1.7965x over previous
//
#include <hip/hip_runtime.h>

// 2-layer tanh RNN, B=64 T=512 H=512, f32 in/out.
// Weights split hi+lo bf16 (w=hi+lo) -> 2 MFMA passes/operand, f32-grade acc.
// Fused pipeline: 64 WGs x 256 thr; blocks 0..31 layer 0, 32..63 layer 1
// (xw1 fused as concat-K MFMA, one step behind layer 0). h rings bf16.
// Protocol history: R4 atomics-everywhere = 10.9us/step (32 SERIALIZED
// ~800cy coherent-point round-trips: each atomic load fed an MFMA directly).
// R5 fence protocol = 19.3us/step (agent __threadfence => buffer_wbl2/inv
// full-cache nukes, 2/WG/step). R6: R4 protocol + ALL fragment loads hoisted
// into register arrays BEFORE any MFMA -> loads pipeline into ONE latency.

#define HD 512
#define BATCH 64
#define SEQ 512
#define NVOCAB 25
#define OUTD 1000
#define NWG 32
#define BH (BATCH * HD)

typedef unsigned short u16;
typedef unsigned int u32;
typedef unsigned long long u64;
typedef __attribute__((ext_vector_type(8))) short short8;  // 8 bf16
typedef __attribute__((ext_vector_type(4))) float f32x4;

union FragU { u16 h[8]; u64 q[2]; short8 v; };

__device__ __forceinline__ float bf2f(u16 v) {
    union { u32 u; float f; } c; c.u = ((u32)v) << 16; return c.f;
}
__device__ __forceinline__ u16 f2bf(float f) {
    union { float f; u32 u; } c; c.f = f;
    return (u16)((c.u + 0x7FFFu + ((c.u >> 16) & 1u)) >> 16);  // RNE
}
__device__ __forceinline__ short8 ld_frag(const u16* p) {
    FragU f; u64* q = (u64*)p;
    f.q[0] = __hip_atomic_load(q + 0, __ATOMIC_RELAXED, __HIP_MEMORY_SCOPE_AGENT);
    f.q[1] = __hip_atomic_load(q + 1, __ATOMIC_RELAXED, __HIP_MEMORY_SCOPE_AGENT);
    return f.v;
}
__device__ __forceinline__ void st_frag4(u16* p, u64 pk) {
    __hip_atomic_store((u64*)p, pk, __ATOMIC_RELAXED, __HIP_MEMORY_SCOPE_AGENT);
}

// Zero header+rings; global thread 1024 probes x's int width:
// int64 little-endian => odd int32 words of small nonneg values are all 0.
__global__ void init_kernel(u32* p, int n, const int* x32, int* flag) {
    int i = blockIdx.x * 256 + threadIdx.x;
    if (i == 1024) {
        int all0 = 1;
        for (int j = 0; j < 64; ++j) if (x32[2 * j + 1] != 0) all0 = 0;
        *flag = all0;
    } else if (i < n) p[i] = 0u;
}

__global__ __launch_bounds__(256, 1) void rnn_fused(
    const float* __restrict__ Whh0, const float* __restrict__ Wih0,
    const int* __restrict__ x,
    const float* __restrict__ bih0, const float* __restrict__ bhh0,
    const float* __restrict__ Whh1, const float* __restrict__ Wih1,
    const float* __restrict__ bih1, const float* __restrict__ bhh1,
    u16* h1ring, u16* h2ring, float* h2final, int* hdr)
{
    int* c0 = hdr;
    int* c1 = hdr + 512;
    const int tid  = threadIdx.x;
    const int wave = tid >> 6;
    const int lane = tid & 63;
    const int quad = lane >> 4;
    const int l16  = lane & 15;
    const int layer = blockIdx.x >> 5;          // 0 or 1
    const int rowbase = (blockIdx.x & 31) * 16; // 32 WGs x 16 rows = 512
    const int arow = rowbase + l16;             // A row (m = lane&15)
    const int row0 = rowbase + quad * 4;        // C/D rows: quad*4 + reg
    const int col  = wave * 16 + l16;           // C/D col (batch)

    __shared__ u16 ldsW[2][16][4][16][8];       // Wih1 hi/lo frags, 32 KB

    // Whh split hi/lo bf16, register-resident: A[m=lane&15][k=quad*8+j].
    const float* Wself = layer ? Whh1 : Whh0;
    short8 Ah[16], Al[16];
    #pragma unroll
    for (int kc = 0; kc < 16; ++kc) {
        FragU th, tl;
        #pragma unroll
        for (int j = 0; j < 8; ++j) {
            float w = Wself[arow * HD + kc * 32 + quad * 8 + j];
            u16 hi = f2bf(w);
            th.h[j] = hi;
            tl.h[j] = f2bf(w - bf2f(hi));
        }
        Ah[kc] = th.v; Al[kc] = tl.v;
    }
    if (layer && wave == 0) {  // all 4 waves share the same A rows
        #pragma unroll
        for (int kc = 0; kc < 16; ++kc) {
            FragU th, tl;
            #pragma unroll
            for (int j = 0; j < 8; ++j) {
                float w = Wih1[arow * HD + kc * 32 + quad * 8 + j];
                u16 hi = f2bf(w);
                th.h[j] = hi;
                tl.h[j] = f2bf(w - bf2f(hi));
            }
            *(short8*)&ldsW[0][kc][quad][l16][0] = th.v;
            *(short8*)&ldsW[1][kc][quad][l16][0] = tl.v;
        }
    }
    const float* bA = layer ? bih1 : bih0;
    const float* bB = layer ? bhh1 : bhh0;
    float bsum[4];
    #pragma unroll
    for (int i = 0; i < 4; ++i) bsum[i] = bA[row0 + i] + bB[row0 + i];
    const int is64 = hdr[1024];
    __syncthreads();

    for (int t = 0; t < SEQ; ++t) {
        // ---- wait: tid0 acquire-spins on producer flags ----
        if (tid == 0) {
            long g = 0;
            if (layer == 0) {
                if (t > 0)
                    while (__hip_atomic_load(c0 + (t - 1), __ATOMIC_ACQUIRE,
                               __HIP_MEMORY_SCOPE_AGENT) < NWG && ++g < (1L << 24)) {}
                if (t >= 2)  // WAR: layer-1 readers of h1[t-1] retired
                    while (__hip_atomic_load(c1 + (t - 2), __ATOMIC_ACQUIRE,
                               __HIP_MEMORY_SCOPE_AGENT) < NWG && ++g < (1L << 24)) {}
            } else {
                if (t > 0)
                    while (__hip_atomic_load(c1 + (t - 1), __ATOMIC_ACQUIRE,
                               __HIP_MEMORY_SCOPE_AGENT) < NWG && ++g < (1L << 24)) {}
                while (__hip_atomic_load(c0 + t, __ATOMIC_ACQUIRE,
                           __HIP_MEMORY_SCOPE_AGENT) < NWG && ++g < (1L << 24)) {}
            }
        }
        __syncthreads();  // all threads held until flags observed

        // ---- compute: LOAD ALL FRAGMENTS FIRST (pipelined), then MFMA ----
        f32x4 acc = {0.f, 0.f, 0.f, 0.f};
        float pre[4];
        if (layer == 0) {
            const u16* hp = h1ring + (size_t)(t & 1) * BH + col * HD;  // h1[t]
            short8 B2[16];
            #pragma unroll
            for (int kc = 0; kc < 16; ++kc)
                B2[kc] = ld_frag(hp + kc * 32 + quad * 8);
            int xi = is64 ? (int)((const long long*)x)[col * SEQ + t]
                          : x[col * SEQ + t];               // x[b][t]
            #pragma unroll
            for (int kc = 0; kc < 16; ++kc) {
                acc = __builtin_amdgcn_mfma_f32_16x16x32_bf16(Ah[kc], B2[kc], acc, 0, 0, 0);
                acc = __builtin_amdgcn_mfma_f32_16x16x32_bf16(Al[kc], B2[kc], acc, 0, 0, 0);
            }
            #pragma unroll
            for (int i = 0; i < 4; ++i)
                pre[i] = acc[i] + bsum[i] + Wih0[(row0 + i) * NVOCAB + xi];
        } else {
            const u16* hp = h2ring + (size_t)(t & 1) * BH + col * HD;        // h2[t]
            const u16* hq = h1ring + (size_t)((t + 1) & 1) * BH + col * HD;  // h1[t+1]
            short8 B2[16], B1[16];
            #pragma unroll
            for (int kc = 0; kc < 16; ++kc)
                B2[kc] = ld_frag(hp + kc * 32 + quad * 8);
            #pragma unroll
            for (int kc = 0; kc < 16; ++kc)
                B1[kc] = ld_frag(hq + kc * 32 + quad * 8);
            #pragma unroll
            for (int kc = 0; kc < 16; ++kc) {
                acc = __builtin_amdgcn_mfma_f32_16x16x32_bf16(Ah[kc], B2[kc], acc, 0, 0, 0);
                acc = __builtin_amdgcn_mfma_f32_16x16x32_bf16(Al[kc], B2[kc], acc, 0, 0, 0);
                short8 w1h = *(short8*)&ldsW[0][kc][quad][l16][0];
                short8 w1l = *(short8*)&ldsW[1][kc][quad][l16][0];
                acc = __builtin_amdgcn_mfma_f32_16x16x32_bf16(w1h, B1[kc], acc, 0, 0, 0);
                acc = __builtin_amdgcn_mfma_f32_16x16x32_bf16(w1l, B1[kc], acc, 0, 0, 0);
            }
            #pragma unroll
            for (int i = 0; i < 4; ++i) pre[i] = acc[i] + bsum[i];
        }
        float hf[4]; u16 hv[4];
        #pragma unroll
        for (int i = 0; i < 4; ++i) { hf[i] = tanhf(pre[i]); hv[i] = f2bf(hf[i]); }
        u64 pk = (u64)hv[0] | ((u64)hv[1] << 16) | ((u64)hv[2] << 32) | ((u64)hv[3] << 48);
        u16* dst = (layer == 0)
            ? h1ring + (size_t)((t + 1) & 1) * BH + col * HD + row0
            : h2ring + (size_t)((t + 1) & 1) * BH + col * HD + row0;
        st_frag4(dst, pk);
        if (layer == 1 && t == SEQ - 1)
            *(f32x4*)(h2final + col * HD + row0) = *(f32x4*)hf;  // exact final h2

        // ---- publish ----
        __syncthreads();  // each wave drains vmcnt before barrier => WG stores done
        if (tid == 0) {
            int* ctr = (layer == 0) ? (c0 + t) : (c1 + t);
            __hip_atomic_fetch_add(ctr, 1, __ATOMIC_RELEASE, __HIP_MEMORY_SCOPE_AGENT);
        }
    }
}

__global__ __launch_bounds__(256) void out_kernel(
    const float* __restrict__ h2last, const float* __restrict__ Wout,
    const float* __restrict__ bout, float* __restrict__ out)
{
    int o = blockIdx.x * 256 + threadIdx.x;
    int b = blockIdx.y;
    if (o >= OUTD) return;
    const float* hrow = h2last + b * HD;
    const float* wrow = Wout + o * HD;
    float acc = 0.f;
    for (int k = 0; k < HD; k += 4) {
        float4 hv = *(const float4*)(hrow + k);
        float4 wv = *(const float4*)(wrow + k);
        acc += hv.x * wv.x + hv.y * wv.y + hv.z * wv.z + hv.w * wv.w;
    }
    out[b * OUTD + o] = acc + bout[o];
}

extern "C" void kernel_launch(void* const* d_in, const int* in_sizes, int n_in,
                              void* d_out, int out_size, void* d_ws, size_t ws_size,
                              hipStream_t stream) {
    const int*   x     = (const int*)d_in[0];
    const float* W_ih0 = (const float*)d_in[1];
    const float* W_hh0 = (const float*)d_in[2];
    const float* b_ih0 = (const float*)d_in[3];
    const float* b_hh0 = (const float*)d_in[4];
    const float* W_ih1 = (const float*)d_in[5];
    const float* W_hh1 = (const float*)d_in[6];
    const float* b_ih1 = (const float*)d_in[7];
    const float* b_hh1 = (const float*)d_in[8];
    const float* W_out = (const float*)d_in[9];
    const float* b_out = (const float*)d_in[10];

    // ws: hdr[2048] int (c0[512] c1[512] flag@1024) | h1ring 2xBH bf16 |
    //     h2ring 2xBH bf16 | h2final BH f32
    const size_t needed = 8192 + (size_t)2 * BH * 2 * 2 + (size_t)BH * 4;  // 392 KB
    if (ws_size < needed) return;  // signature: absmax=0.149 non-NaN => ws short

    int* hdr = (int*)d_ws;
    u16* h1ring = (u16*)((char*)d_ws + 8192);
    u16* h2ring = h1ring + (size_t)2 * BH;
    float* h2final = (float*)(h2ring + (size_t)2 * BH);

    const int nzero = (8192 + 4 * BH * 2) / 4;  // hdr + both rings, in words
    init_kernel<<<(nzero + 255) / 256, 256, 0, stream>>>((u32*)d_ws, nzero, x, hdr + 1024);
    rnn_fused<<<2 * NWG, 256, 0, stream>>>(W_hh0, W_ih0, x, b_ih0, b_hh0,
                                           W_hh1, W_ih1, b_ih1, b_hh1,
                                           h1ring, h2ring, h2final, hdr);
    out_kernel<<<dim3(4, BATCH), 256, 0, stream>>>(h2final, W_out, b_out, (float*)d_out);
}

// Round 7
// 4579.942 us; speedup vs baseline: 2.1491x; 1.1963x over previous
//
#include <hip/hip_runtime.h>

// 2-layer tanh RNN, B=64 T=512 H=512, f32 in/out.
// Weights split hi+lo bf16 (w=hi+lo) -> 2 MFMA passes/operand, f32-grade acc.
// Fused pipeline: 64 WGs x 256 thr; blocks 0..31 layer 0, 32..63 layer 1
// (xw1 fused as concat-K MFMA, one step behind layer 0). h rings bf16,
// cross-WG via coherent-point (agent-scope relaxed atomic) loads/stores.
// Sync history: R4/R6 = 10.6us/step with 32 atomicAdds on ONE counter line
// under 64 spinners (line ping-pong ~7us/step). R7: per-WG cache-line-padded
// monotonic flags (plain atomic store, one writer/line) + one-wave parallel
// poll of all 32 flags via __ballot -> one IF$ round trip per handoff.

#define HD 512
#define BATCH 64
#define SEQ 512
#define NVOCAB 25
#define OUTD 1000
#define NWG 32
#define BH (BATCH * HD)
#define FPAD 16  // ints per flag slot (64 B line)

typedef unsigned short u16;
typedef unsigned int u32;
typedef unsigned long long u64;
typedef __attribute__((ext_vector_type(8))) short short8;  // 8 bf16
typedef __attribute__((ext_vector_type(4))) float f32x4;

union FragU { u16 h[8]; u64 q[2]; short8 v; };

__device__ __forceinline__ float bf2f(u16 v) {
    union { u32 u; float f; } c; c.u = ((u32)v) << 16; return c.f;
}
__device__ __forceinline__ u16 f2bf(float f) {
    union { float f; u32 u; } c; c.f = f;
    return (u16)((c.u + 0x7FFFu + ((c.u >> 16) & 1u)) >> 16);  // RNE
}
__device__ __forceinline__ short8 ld_frag(const u16* p) {
    FragU f; u64* q = (u64*)p;
    f.q[0] = __hip_atomic_load(q + 0, __ATOMIC_RELAXED, __HIP_MEMORY_SCOPE_AGENT);
    f.q[1] = __hip_atomic_load(q + 1, __ATOMIC_RELAXED, __HIP_MEMORY_SCOPE_AGENT);
    return f.v;
}

// Zero header+rings; global thread 1024 probes x's int width:
// int64 little-endian => odd int32 words of small nonneg values are all 0.
__global__ void init_kernel(u32* p, int n, const int* x32, int* flag) {
    int i = blockIdx.x * 256 + threadIdx.x;
    if (i == 1024) {
        int all0 = 1;
        for (int j = 0; j < 64; ++j) if (x32[2 * j + 1] != 0) all0 = 0;
        *flag = all0;
    } else if (i < n) p[i] = 0u;
}

// hdr layout (ints): flags0[32*FPAD] | flags1[32*FPAD] | is64 @ [1024]
__global__ __launch_bounds__(256, 1) void rnn_fused(
    const float* __restrict__ Whh0, const float* __restrict__ Wih0,
    const int* __restrict__ x,
    const float* __restrict__ bih0, const float* __restrict__ bhh0,
    const float* __restrict__ Whh1, const float* __restrict__ Wih1,
    const float* __restrict__ bih1, const float* __restrict__ bhh1,
    u16* h1ring, u16* h2ring, float* h2final, int* hdr)
{
    int* flags0 = hdr;                 // layer-0 WG g completed step t => flags0[g*FPAD] == t+1
    int* flags1 = hdr + NWG * FPAD;    // same for layer 1
    const int tid  = threadIdx.x;
    const int wave = tid >> 6;
    const int lane = tid & 63;
    const int quad = lane >> 4;
    const int l16  = lane & 15;
    const int layer = blockIdx.x >> 5;          // 0 or 1
    const int rowbase = (blockIdx.x & 31) * 16; // 32 WGs x 16 rows = 512
    const int arow = rowbase + l16;             // A row (m = lane&15)
    const int row0 = rowbase + quad * 4;        // C/D rows: quad*4 + reg
    const int col  = wave * 16 + l16;           // C/D col (batch)
    int* myflag = (layer ? flags1 : flags0) + (blockIdx.x & 31) * FPAD;

    __shared__ u16 ldsW[2][16][4][16][8];       // Wih1 hi/lo frags, 32 KB

    // Whh split hi/lo bf16, register-resident: A[m=lane&15][k=quad*8+j].
    const float* Wself = layer ? Whh1 : Whh0;
    short8 Ah[16], Al[16];
    #pragma unroll
    for (int kc = 0; kc < 16; ++kc) {
        FragU th, tl;
        #pragma unroll
        for (int j = 0; j < 8; ++j) {
            float w = Wself[arow * HD + kc * 32 + quad * 8 + j];
            u16 hi = f2bf(w);
            th.h[j] = hi;
            tl.h[j] = f2bf(w - bf2f(hi));
        }
        Ah[kc] = th.v; Al[kc] = tl.v;
    }
    if (layer && wave == 0) {  // all 4 waves share the same A rows
        #pragma unroll
        for (int kc = 0; kc < 16; ++kc) {
            FragU th, tl;
            #pragma unroll
            for (int j = 0; j < 8; ++j) {
                float w = Wih1[arow * HD + kc * 32 + quad * 8 + j];
                u16 hi = f2bf(w);
                th.h[j] = hi;
                tl.h[j] = f2bf(w - bf2f(hi));
            }
            *(short8*)&ldsW[0][kc][quad][l16][0] = th.v;
            *(short8*)&ldsW[1][kc][quad][l16][0] = tl.v;
        }
    }
    const float* bA = layer ? bih1 : bih0;
    const float* bB = layer ? bhh1 : bhh0;
    float bsum[4];
    #pragma unroll
    for (int i = 0; i < 4; ++i) bsum[i] = bA[row0 + i] + bB[row0 + i];
    const int is64 = hdr[1024];
    __syncthreads();

    for (int t = 0; t < SEQ; ++t) {
        // ---- wait: wave 0 polls all 32+32 per-WG flags in parallel ----
        // layer0: peers flags0 >= t (h1[t] done), WAR flags1 >= t-1
        //         (layer-1 readers of slot (t+1)&1 retired).
        // layer1: peers flags1 >= t (h2[t] done), prod flags0 >= t+1 (h1[t+1]).
        if (wave == 0) {
            const int g = lane & 31;
            int* p; int tgt;
            if (layer == 0) { p = (lane < 32 ? flags0 : flags1) + g * FPAD;
                              tgt = (lane < 32) ? t : (t - 1); }
            else            { p = (lane < 32 ? flags1 : flags0) + g * FPAD;
                              tgt = (lane < 32) ? t : (t + 1); }
            long guard = 0;
            while (__ballot(__hip_atomic_load(p, __ATOMIC_RELAXED,
                       __HIP_MEMORY_SCOPE_AGENT) < tgt) != 0ULL &&
                   ++guard < (1L << 24)) {}
        }
        __syncthreads();

        // ---- compute: load all fragments first (pipelined), then MFMA ----
        f32x4 acc = {0.f, 0.f, 0.f, 0.f};
        float pre[4];
        if (layer == 0) {
            const u16* hp = h1ring + (size_t)(t & 1) * BH + col * HD;  // h1[t]
            short8 B2[16];
            #pragma unroll
            for (int kc = 0; kc < 16; ++kc)
                B2[kc] = ld_frag(hp + kc * 32 + quad * 8);
            int xi = is64 ? (int)((const long long*)x)[col * SEQ + t]
                          : x[col * SEQ + t];               // x[b][t]
            #pragma unroll
            for (int kc = 0; kc < 16; ++kc) {
                acc = __builtin_amdgcn_mfma_f32_16x16x32_bf16(Ah[kc], B2[kc], acc, 0, 0, 0);
                acc = __builtin_amdgcn_mfma_f32_16x16x32_bf16(Al[kc], B2[kc], acc, 0, 0, 0);
            }
            #pragma unroll
            for (int i = 0; i < 4; ++i)
                pre[i] = acc[i] + bsum[i] + Wih0[(row0 + i) * NVOCAB + xi];
        } else {
            const u16* hp = h2ring + (size_t)(t & 1) * BH + col * HD;        // h2[t]
            const u16* hq = h1ring + (size_t)((t + 1) & 1) * BH + col * HD;  // h1[t+1]
            short8 B2[16], B1[16];
            #pragma unroll
            for (int kc = 0; kc < 16; ++kc)
                B2[kc] = ld_frag(hp + kc * 32 + quad * 8);
            #pragma unroll
            for (int kc = 0; kc < 16; ++kc)
                B1[kc] = ld_frag(hq + kc * 32 + quad * 8);
            #pragma unroll
            for (int kc = 0; kc < 16; ++kc) {
                acc = __builtin_amdgcn_mfma_f32_16x16x32_bf16(Ah[kc], B2[kc], acc, 0, 0, 0);
                acc = __builtin_amdgcn_mfma_f32_16x16x32_bf16(Al[kc], B2[kc], acc, 0, 0, 0);
                short8 w1h = *(short8*)&ldsW[0][kc][quad][l16][0];
                short8 w1l = *(short8*)&ldsW[1][kc][quad][l16][0];
                acc = __builtin_amdgcn_mfma_f32_16x16x32_bf16(w1h, B1[kc], acc, 0, 0, 0);
                acc = __builtin_amdgcn_mfma_f32_16x16x32_bf16(w1l, B1[kc], acc, 0, 0, 0);
            }
            #pragma unroll
            for (int i = 0; i < 4; ++i) pre[i] = acc[i] + bsum[i];
        }
        float hf[4]; u16 hv[4];
        #pragma unroll
        for (int i = 0; i < 4; ++i) { hf[i] = tanhf(pre[i]); hv[i] = f2bf(hf[i]); }
        u64 pk = (u64)hv[0] | ((u64)hv[1] << 16) | ((u64)hv[2] << 32) | ((u64)hv[3] << 48);
        u16* dst = (layer == 0)
            ? h1ring + (size_t)((t + 1) & 1) * BH + col * HD + row0
            : h2ring + (size_t)((t + 1) & 1) * BH + col * HD + row0;
        __hip_atomic_store((u64*)dst, pk, __ATOMIC_RELAXED, __HIP_MEMORY_SCOPE_AGENT);
        if (layer == 1 && t == SEQ - 1)
            *(f32x4*)(h2final + col * HD + row0) = *(f32x4*)hf;  // exact final h2

        // ---- publish: barrier drains vmcnt (h at coherent point), then flag ----
        __syncthreads();
        if (tid == 0)
            __hip_atomic_store(myflag, t + 1, __ATOMIC_RELEASE,
                               __HIP_MEMORY_SCOPE_AGENT);
    }
}

__global__ __launch_bounds__(256) void out_kernel(
    const float* __restrict__ h2last, const float* __restrict__ Wout,
    const float* __restrict__ bout, float* __restrict__ out)
{
    int o = blockIdx.x * 256 + threadIdx.x;
    int b = blockIdx.y;
    if (o >= OUTD) return;
    const float* hrow = h2last + b * HD;
    const float* wrow = Wout + o * HD;
    float acc = 0.f;
    for (int k = 0; k < HD; k += 4) {
        float4 hv = *(const float4*)(hrow + k);
        float4 wv = *(const float4*)(wrow + k);
        acc += hv.x * wv.x + hv.y * wv.y + hv.z * wv.z + hv.w * wv.w;
    }
    out[b * OUTD + o] = acc + bout[o];
}

extern "C" void kernel_launch(void* const* d_in, const int* in_sizes, int n_in,
                              void* d_out, int out_size, void* d_ws, size_t ws_size,
                              hipStream_t stream) {
    const int*   x     = (const int*)d_in[0];
    const float* W_ih0 = (const float*)d_in[1];
    const float* W_hh0 = (const float*)d_in[2];
    const float* b_ih0 = (const float*)d_in[3];
    const float* b_hh0 = (const float*)d_in[4];
    const float* W_ih1 = (const float*)d_in[5];
    const float* W_hh1 = (const float*)d_in[6];
    const float* b_ih1 = (const float*)d_in[7];
    const float* b_hh1 = (const float*)d_in[8];
    const float* W_out = (const float*)d_in[9];
    const float* b_out = (const float*)d_in[10];

    // ws: hdr[2048] int (flags0/flags1 padded, is64 @1024) | h1ring 2xBH bf16 |
    //     h2ring 2xBH bf16 | h2final BH f32
    const size_t needed = 8192 + (size_t)2 * BH * 2 * 2 + (size_t)BH * 4;  // 392 KB
    if (ws_size < needed) return;  // signature: absmax=0.149 non-NaN => ws short

    int* hdr = (int*)d_ws;
    u16* h1ring = (u16*)((char*)d_ws + 8192);
    u16* h2ring = h1ring + (size_t)2 * BH;
    float* h2final = (float*)(h2ring + (size_t)2 * BH);

    const int nzero = (8192 + 4 * BH * 2) / 4;  // hdr + both rings, in words
    init_kernel<<<(nzero + 255) / 256, 256, 0, stream>>>((u32*)d_ws, nzero, x, hdr + 1024);
    rnn_fused<<<2 * NWG, 256, 0, stream>>>(W_hh0, W_ih0, x, b_ih0, b_hh0,
                                           W_hh1, W_ih1, b_ih1, b_hh1,
                                           h1ring, h2ring, h2final, hdr);
    out_kernel<<<dim3(4, BATCH), 256, 0, stream>>>(h2final, W_out, b_out, (float*)d_out);
}